// Round 1
// baseline (1560.282 us; speedup 1.0000x reference)
//
#include <hip/hip_runtime.h>

#define THREADS 256

__device__ __forceinline__ unsigned short f2bf(float f) {
  unsigned int u = __float_as_uint(f);
  u += 0x7fffu + ((u >> 16) & 1u);
  return (unsigned short)(u >> 16);
}
__device__ __forceinline__ float bf2f(unsigned short h) {
  return __uint_as_float(((unsigned int)h) << 16);
}

// ---------------- degree count ----------------
__global__ void k_count(const int* __restrict__ dst, int E, int* __restrict__ deg) {
  int e = blockIdx.x * THREADS + threadIdx.x;
  if (e < E) atomicAdd(&deg[dst[e]], 1);
}

__global__ void k_dis(const int* __restrict__ deg, float* __restrict__ dis, int n) {
  int i = blockIdx.x * THREADS + threadIdx.x;
  if (i < n) dis[i] = rsqrtf((float)(deg[i] + 1));  // +1 self loop
}

// ---------------- exclusive scan (1024 elems / block) ----------------
__global__ void k_scan_partial(const int* __restrict__ deg, int n, int* __restrict__ part) {
  __shared__ int sd[THREADS];
  int t = threadIdx.x;
  int base = blockIdx.x * 1024 + t * 4;
  int s = 0;
#pragma unroll
  for (int j = 0; j < 4; ++j) { int idx = base + j; if (idx < n) s += deg[idx]; }
  sd[t] = s;
  __syncthreads();
  for (int off = 128; off > 0; off >>= 1) {
    if (t < off) sd[t] += sd[t + off];
    __syncthreads();
  }
  if (t == 0) part[blockIdx.x] = sd[0];
}

__global__ void k_scan_mid(int* part, int nb) {
  if (threadIdx.x == 0 && blockIdx.x == 0) {
    int run = 0;
    for (int i = 0; i < nb; ++i) { int v = part[i]; part[i] = run; run += v; }
  }
}

__global__ void k_scan_final(const int* __restrict__ deg, int n, const int* __restrict__ part,
                             int* __restrict__ rowptr) {
  __shared__ int sa[THREADS], sb[THREADS];
  int t = threadIdx.x;
  int base = blockIdx.x * 1024 + t * 4;
  int v[4]; int s = 0;
#pragma unroll
  for (int j = 0; j < 4; ++j) { int idx = base + j; v[j] = (idx < n) ? deg[idx] : 0; s += v[j]; }
  sa[t] = s;
  __syncthreads();
  int* cur = sa; int* nxt = sb;
  for (int off = 1; off < 256; off <<= 1) {
    int val = cur[t];
    if (t >= off) val += cur[t - off];
    nxt[t] = val;
    __syncthreads();
    int* tmp = cur; cur = nxt; nxt = tmp;
  }
  int pref = part[blockIdx.x] + cur[t] - s;  // exclusive prefix for this thread
#pragma unroll
  for (int j = 0; j < 4; ++j) {
    int idx = base + j;
    if (idx < n) rowptr[idx] = pref;
    pref += v[j];
  }
}

// ---------------- CSR fill ----------------
__global__ void k_fill(const int* __restrict__ src, const int* __restrict__ dst, int E,
                       const int* __restrict__ rowptr, int* __restrict__ cursor,
                       int* __restrict__ csr) {
  int e = blockIdx.x * THREADS + threadIdx.x;
  if (e < E) {
    int d = dst[e];
    int pos = atomicAdd(&cursor[d], 1);
    csr[rowptr[d] + pos] = src[e];
  }
}

// ---------------- agg1: Y[d] = dis[d]*(sum_e dis[s]*X[s] + dis[d]*X[d]) ----------------
// X = [latent | condition], 256 channels. One wave per node; half-wave per input.
__global__ void k_agg1(const float4* __restrict__ lat4, const float4* __restrict__ con4,
                       const int* __restrict__ rowptr, const int* __restrict__ deg,
                       const int* __restrict__ csr, const float* __restrict__ dis,
                       float4* __restrict__ Y4, int n) {
  int tid = threadIdx.x;
  int d = blockIdx.x * 4 + (tid >> 6);
  if (d >= n) return;
  int lane = tid & 63;
  int half = lane >> 5;
  int li = lane & 31;
  const float4* base = half ? con4 : lat4;
  float4 acc = make_float4(0.f, 0.f, 0.f, 0.f);
  int beg = rowptr[d];
  int end = beg + deg[d];
  int i = beg;
  for (; i + 4 <= end; i += 4) {
    int s0 = csr[i], s1 = csr[i + 1], s2 = csr[i + 2], s3 = csr[i + 3];
    float w0 = dis[s0], w1 = dis[s1], w2 = dis[s2], w3 = dis[s3];
    float4 v0 = base[s0 * 32 + li];
    float4 v1 = base[s1 * 32 + li];
    float4 v2 = base[s2 * 32 + li];
    float4 v3 = base[s3 * 32 + li];
    acc.x += w0 * v0.x + w1 * v1.x + w2 * v2.x + w3 * v3.x;
    acc.y += w0 * v0.y + w1 * v1.y + w2 * v2.y + w3 * v3.y;
    acc.z += w0 * v0.z + w1 * v1.z + w2 * v2.z + w3 * v3.z;
    acc.w += w0 * v0.w + w1 * v1.w + w2 * v2.w + w3 * v3.w;
  }
  for (; i < end; ++i) {
    int s = csr[i];
    float w = dis[s];
    float4 v = base[s * 32 + li];
    acc.x += w * v.x; acc.y += w * v.y; acc.z += w * v.z; acc.w += w * v.w;
  }
  float wd = dis[d];
  float4 vd = base[d * 32 + li];
  acc.x = (acc.x + wd * vd.x) * wd;
  acc.y = (acc.y + wd * vd.y) * wd;
  acc.z = (acc.z + wd * vd.z) * wd;
  acc.w = (acc.w + wd * vd.w) * wd;
  Y4[(size_t)d * 64 + half * 32 + li] = acc;
}

// ---------------- GEMM1 (in place): H = tanh([Yz@Wz + bz | Yc@Wc + bc]) as bf16 ----------------
// Y rows: 256 f32 (1KB). H rows: 512 bf16 (1KB). Block = 32 rows, in-place over same bytes.
__global__ __launch_bounds__(THREADS) void k_gemm1(const float* Y, unsigned short* Hout,
                                                   const float* __restrict__ Wz,
                                                   const float* __restrict__ bz,
                                                   const float* __restrict__ Wc,
                                                   const float* __restrict__ bc) {
  __shared__ float ldsA[256 * 36];   // [k=Ycol][row], pad 36 keeps 16B align
  __shared__ float ldsB[16 * 256];   // W chunk: 16 k-rows x 256 cols
  int t = threadIdx.x;
  int rowbase = blockIdx.x * 32;
  const float* Yblk = Y + (size_t)rowbase * 256;
#pragma unroll
  for (int j = 0; j < 32; ++j) ldsA[t * 36 + j] = Yblk[j * 256 + t];  // col t, row j
  __syncthreads();
  int r0 = (t >> 6) * 8;       // 4 row-groups x 8 rows
  int c0 = (t & 63) * 4;       // 64 col-groups x 4 cols
  for (int half = 0; half < 2; ++half) {
    const float* W = half ? Wc : Wz;
    float acc[8][4];
#pragma unroll
    for (int r = 0; r < 8; ++r)
#pragma unroll
      for (int c = 0; c < 4; ++c) acc[r][c] = 0.f;
    for (int kc = 0; kc < 128; kc += 16) {
      __syncthreads();
#pragma unroll
      for (int j = 0; j < 16; ++j) ldsB[j * 256 + t] = W[(kc + j) * 256 + t];
      __syncthreads();
#pragma unroll
      for (int kk = 0; kk < 16; ++kk) {
        int ka = half * 128 + kc + kk;
        float a[8], b4[4];
        *(float4*)&a[0] = *(const float4*)&ldsA[ka * 36 + r0];
        *(float4*)&a[4] = *(const float4*)&ldsA[ka * 36 + r0 + 4];
        *(float4*)&b4[0] = *(const float4*)&ldsB[kk * 256 + c0];
#pragma unroll
        for (int r = 0; r < 8; ++r)
#pragma unroll
          for (int c = 0; c < 4; ++c) acc[r][c] += a[r] * b4[c];
      }
    }
    const float* bias = half ? bc : bz;
    float4 bi = *(const float4*)&bias[c0];
    float bb[4] = { bi.x, bi.y, bi.z, bi.w };
#pragma unroll
    for (int r = 0; r < 8; ++r) {
      ushort4 hv;
      hv.x = f2bf(tanhf(acc[r][0] + bb[0]));
      hv.y = f2bf(tanhf(acc[r][1] + bb[1]));
      hv.z = f2bf(tanhf(acc[r][2] + bb[2]));
      hv.w = f2bf(tanhf(acc[r][3] + bb[3]));
      *(ushort4*)&Hout[(size_t)(rowbase + r0 + r) * 512 + half * 256 + c0] = hv;
    }
  }
}

// ---------------- GEMM2: G3[n] = dis[n] * (H[n] @ Wo), H bf16 [N,512], out f32 [N,128] ------
__global__ __launch_bounds__(THREADS) void k_gemm2(const unsigned short* __restrict__ H,
                                                   const float* __restrict__ Wo,
                                                   const float* __restrict__ dis,
                                                   float* __restrict__ G3) {
  __shared__ unsigned short ldsA[512 * 36];  // [k=Hcol][row] bf16, pad 36 keeps 8B align
  __shared__ float ldsB[32 * 128];           // Wo chunk: 32 k-rows x 128 cols
  int t = threadIdx.x;
  int rowbase = blockIdx.x * 32;
  const ushort2* Hblk = (const ushort2*)(H + (size_t)rowbase * 512);
#pragma unroll
  for (int j = 0; j < 32; ++j) {
    ushort2 v = Hblk[j * 256 + t];  // row j, cols 2t,2t+1
    ldsA[(2 * t) * 36 + j] = v.x;
    ldsA[(2 * t + 1) * 36 + j] = v.y;
  }
  __syncthreads();
  int r0 = (t >> 5) * 4;   // 8 row-groups x 4 rows
  int c0 = (t & 31) * 4;   // 32 col-groups x 4 cols
  float acc[4][4];
#pragma unroll
  for (int r = 0; r < 4; ++r)
#pragma unroll
    for (int c = 0; c < 4; ++c) acc[r][c] = 0.f;
  for (int kc = 0; kc < 512; kc += 32) {
    __syncthreads();
#pragma unroll
    for (int j = 0; j < 16; ++j) {
      int idx = j * 256 + t;  // 32 rows x 128 cols
      ldsB[idx] = Wo[(size_t)kc * 128 + idx];
    }
    __syncthreads();
#pragma unroll
    for (int kk = 0; kk < 32; ++kk) {
      int ka = kc + kk;
      ushort4 au = *(const ushort4*)&ldsA[ka * 36 + r0];
      float a[4] = { bf2f(au.x), bf2f(au.y), bf2f(au.z), bf2f(au.w) };
      float b4[4];
      *(float4*)&b4[0] = *(const float4*)&ldsB[kk * 128 + c0];
#pragma unroll
      for (int r = 0; r < 4; ++r)
#pragma unroll
        for (int c = 0; c < 4; ++c) acc[r][c] += a[r] * b4[c];
    }
  }
#pragma unroll
  for (int r = 0; r < 4; ++r) {
    float dd = dis[rowbase + r0 + r];
    float4 o;
    o.x = acc[r][0] * dd; o.y = acc[r][1] * dd; o.z = acc[r][2] * dd; o.w = acc[r][3] * dd;
    *(float4*)&G3[(size_t)(rowbase + r0 + r) * 128 + c0] = o;
  }
}

// ---------------- agg2: out[d] = dis[d]*(sum_e G3[s] + G3[d]) + bo ----------------
__global__ void k_agg2(const float2* __restrict__ G2, const int* __restrict__ rowptr,
                       const int* __restrict__ deg, const int* __restrict__ csr,
                       const float* __restrict__ dis, const float* __restrict__ bo,
                       float2* __restrict__ out2, int n) {
  int tid = threadIdx.x;
  int d = blockIdx.x * 4 + (tid >> 6);
  if (d >= n) return;
  int lane = tid & 63;
  float2 acc = make_float2(0.f, 0.f);
  int beg = rowptr[d];
  int end = beg + deg[d];
  int i = beg;
  for (; i + 4 <= end; i += 4) {
    int s0 = csr[i], s1 = csr[i + 1], s2 = csr[i + 2], s3 = csr[i + 3];
    float2 v0 = G2[(size_t)s0 * 64 + lane];
    float2 v1 = G2[(size_t)s1 * 64 + lane];
    float2 v2 = G2[(size_t)s2 * 64 + lane];
    float2 v3 = G2[(size_t)s3 * 64 + lane];
    acc.x += v0.x + v1.x + v2.x + v3.x;
    acc.y += v0.y + v1.y + v2.y + v3.y;
  }
  for (; i < end; ++i) {
    int s = csr[i];
    float2 v = G2[(size_t)s * 64 + lane];
    acc.x += v.x; acc.y += v.y;
  }
  float2 vd = G2[(size_t)d * 64 + lane];
  float wd = dis[d];
  float2 bb = ((const float2*)bo)[lane];
  acc.x = (acc.x + vd.x) * wd + bb.x;
  acc.y = (acc.y + vd.y) * wd + bb.y;
  out2[(size_t)d * 64 + lane] = acc;
}

extern "C" void kernel_launch(void* const* d_in, const int* in_sizes, int n_in,
                              void* d_out, int out_size, void* d_ws, size_t ws_size,
                              hipStream_t stream) {
  const float* latent    = (const float*)d_in[0];
  const float* condition = (const float*)d_in[1];
  const int*   edges     = (const int*)d_in[2];
  const float* Wz        = (const float*)d_in[3];
  const float* bz        = (const float*)d_in[4];
  const float* Wc        = (const float*)d_in[5];
  const float* bc        = (const float*)d_in[6];
  const float* Wo        = (const float*)d_in[7];
  const float* bo        = (const float*)d_in[8];
  float* out = (float*)d_out;

  int n = in_sizes[0] / 128;      // 100000
  int E = in_sizes[2] / 2;        // 3200000
  const int* src = edges;
  const int* dst = edges + E;

  auto align_up = [](size_t x) { return (x + 255) & ~(size_t)255; };
  char* p = (char*)d_ws;
  int* csr     = (int*)p;   p += align_up((size_t)E * 4);
  int* rowptr  = (int*)p;   p += align_up((size_t)n * 4);
  int* deg     = (int*)p;   p += align_up((size_t)n * 4);
  int* cursor  = (int*)p;   p += align_up((size_t)n * 4);
  float* dis   = (float*)p; p += align_up((size_t)n * 4);
  int* part    = (int*)p;   p += 4096;
  float* YH    = (float*)p; p += align_up((size_t)n * 256 * 4);
  float* G3    = (float*)p; p += align_up((size_t)n * 128 * 4);
  (void)ws_size; (void)n_in; (void)out_size;

  hipMemsetAsync(deg, 0, (size_t)n * 4, stream);
  hipMemsetAsync(cursor, 0, (size_t)n * 4, stream);

  int gE = (E + THREADS - 1) / THREADS;
  int gN = (n + THREADS - 1) / THREADS;
  int nb = (n + 1023) / 1024;

  k_count<<<gE, THREADS, 0, stream>>>(dst, E, deg);
  k_dis<<<gN, THREADS, 0, stream>>>(deg, dis, n);
  k_scan_partial<<<nb, THREADS, 0, stream>>>(deg, n, part);
  k_scan_mid<<<1, 64, 0, stream>>>(part, nb);
  k_scan_final<<<nb, THREADS, 0, stream>>>(deg, n, part, rowptr);
  k_fill<<<gE, THREADS, 0, stream>>>(src, dst, E, rowptr, cursor, csr);

  k_agg1<<<(n + 3) / 4, THREADS, 0, stream>>>((const float4*)latent, (const float4*)condition,
                                              rowptr, deg, csr, dis, (float4*)YH, n);
  k_gemm1<<<n / 32, THREADS, 0, stream>>>(YH, (unsigned short*)YH, Wz, bz, Wc, bc);
  k_gemm2<<<n / 32, THREADS, 0, stream>>>((const unsigned short*)YH, Wo, dis, G3);
  k_agg2<<<(n + 3) / 4, THREADS, 0, stream>>>((const float2*)G3, rowptr, deg, csr, dis, bo,
                                              (float2*)out, n);
}

// Round 2
// 1236.206 us; speedup vs baseline: 1.2622x; 1.2622x over previous
//
#include <hip/hip_runtime.h>

#define THREADS 256

__device__ __forceinline__ unsigned short f2bf(float f) {
  unsigned int u = __float_as_uint(f);
  u += 0x7fffu + ((u >> 16) & 1u);
  return (unsigned short)(u >> 16);
}
__device__ __forceinline__ float bf2f(unsigned short h) {
  return __uint_as_float(((unsigned int)h) << 16);
}

// ---------------- degree count ----------------
__global__ void k_count(const int* __restrict__ dst, int E, int* __restrict__ deg) {
  int e = blockIdx.x * THREADS + threadIdx.x;
  if (e < E) atomicAdd(&deg[dst[e]], 1);
}

__global__ void k_dis(const int* __restrict__ deg, float* __restrict__ dis, int n) {
  int i = blockIdx.x * THREADS + threadIdx.x;
  if (i < n) dis[i] = rsqrtf((float)(deg[i] + 1));  // +1 self loop
}

// ---------------- exclusive scan (1024 elems / block) ----------------
__global__ void k_scan_partial(const int* __restrict__ deg, int n, int* __restrict__ part) {
  __shared__ int sd[THREADS];
  int t = threadIdx.x;
  int base = blockIdx.x * 1024 + t * 4;
  int s = 0;
#pragma unroll
  for (int j = 0; j < 4; ++j) { int idx = base + j; if (idx < n) s += deg[idx]; }
  sd[t] = s;
  __syncthreads();
  for (int off = 128; off > 0; off >>= 1) {
    if (t < off) sd[t] += sd[t + off];
    __syncthreads();
  }
  if (t == 0) part[blockIdx.x] = sd[0];
}

__global__ void k_scan_mid(int* part, int nb) {
  if (threadIdx.x == 0 && blockIdx.x == 0) {
    int run = 0;
    for (int i = 0; i < nb; ++i) { int v = part[i]; part[i] = run; run += v; }
  }
}

__global__ void k_scan_final(const int* __restrict__ deg, int n, const int* __restrict__ part,
                             int* __restrict__ rowptr) {
  __shared__ int sa[THREADS], sb[THREADS];
  int t = threadIdx.x;
  int base = blockIdx.x * 1024 + t * 4;
  int v[4]; int s = 0;
#pragma unroll
  for (int j = 0; j < 4; ++j) { int idx = base + j; v[j] = (idx < n) ? deg[idx] : 0; s += v[j]; }
  sa[t] = s;
  __syncthreads();
  int* cur = sa; int* nxt = sb;
  for (int off = 1; off < 256; off <<= 1) {
    int val = cur[t];
    if (t >= off) val += cur[t - off];
    nxt[t] = val;
    __syncthreads();
    int* tmp = cur; cur = nxt; nxt = tmp;
  }
  int pref = part[blockIdx.x] + cur[t] - s;  // exclusive prefix for this thread
#pragma unroll
  for (int j = 0; j < 4; ++j) {
    int idx = base + j;
    if (idx < n) rowptr[idx] = pref;
    pref += v[j];
  }
}

// ---------------- CSR fill ----------------
__global__ void k_fill(const int* __restrict__ src, const int* __restrict__ dst, int E,
                       const int* __restrict__ rowptr, int* __restrict__ cursor,
                       int* __restrict__ csr) {
  int e = blockIdx.x * THREADS + threadIdx.x;
  if (e < E) {
    int d = dst[e];
    int pos = atomicAdd(&cursor[d], 1);
    csr[rowptr[d] + pos] = src[e];
  }
}

// ---------------- cast: XB[s] = bf16( dis[s] * [latent|condition][s] ), row=256 bf16 ----
__global__ void k_cast(const float4* __restrict__ lat4, const float4* __restrict__ con4,
                       const float* __restrict__ dis, ushort4* __restrict__ XB, int n) {
  int tid = threadIdx.x;
  int d = blockIdx.x * 4 + (tid >> 6);
  if (d >= n) return;
  int li = tid & 63;
  float w = dis[d];
  float4 v = (li < 32) ? lat4[(size_t)d * 32 + li] : con4[(size_t)d * 32 + (li - 32)];
  ushort4 o;
  o.x = f2bf(v.x * w); o.y = f2bf(v.y * w); o.z = f2bf(v.z * w); o.w = f2bf(v.w * w);
  XB[(size_t)d * 64 + li] = o;
}

// ---------------- agg1: Y[d] = dis[d]*(sum_e XB[s] + XB[d]), fp32 out ----------------
// XB row = 512B bf16. One wave per node, 8B/lane; unroll 8 for MLP.
__global__ void k_agg1(const ushort4* __restrict__ XB, const int* __restrict__ rowptr,
                       const int* __restrict__ deg, const int* __restrict__ csr,
                       const float* __restrict__ dis, float4* __restrict__ Y4, int n) {
  int tid = threadIdx.x;
  int d = blockIdx.x * 4 + (tid >> 6);
  if (d >= n) return;
  int li = tid & 63;
  float a0 = 0.f, a1 = 0.f, a2 = 0.f, a3 = 0.f;
  int beg = rowptr[d];
  int end = beg + deg[d];
  int i = beg;
  for (; i + 8 <= end; i += 8) {
    int s[8]; ushort4 v[8];
#pragma unroll
    for (int j = 0; j < 8; ++j) s[j] = csr[i + j];
#pragma unroll
    for (int j = 0; j < 8; ++j) v[j] = XB[(size_t)s[j] * 64 + li];
#pragma unroll
    for (int j = 0; j < 8; ++j) {
      a0 += bf2f(v[j].x); a1 += bf2f(v[j].y); a2 += bf2f(v[j].z); a3 += bf2f(v[j].w);
    }
  }
  for (; i < end; ++i) {
    ushort4 v = XB[(size_t)csr[i] * 64 + li];
    a0 += bf2f(v.x); a1 += bf2f(v.y); a2 += bf2f(v.z); a3 += bf2f(v.w);
  }
  ushort4 vd = XB[(size_t)d * 64 + li];
  float wd = dis[d];
  float4 o;
  o.x = (a0 + bf2f(vd.x)) * wd;
  o.y = (a1 + bf2f(vd.y)) * wd;
  o.z = (a2 + bf2f(vd.z)) * wd;
  o.w = (a3 + bf2f(vd.w)) * wd;
  Y4[(size_t)d * 64 + li] = o;
}

// ---------------- GEMM1 (in place): H = tanh([Yz@Wz + bz | Yc@Wc + bc]) as bf16 ----------------
__global__ __launch_bounds__(THREADS) void k_gemm1(const float* Y, unsigned short* Hout,
                                                   const float* __restrict__ Wz,
                                                   const float* __restrict__ bz,
                                                   const float* __restrict__ Wc,
                                                   const float* __restrict__ bc) {
  __shared__ float ldsA[256 * 36];   // [k=Ycol][row], pad 36 keeps 16B align
  __shared__ float ldsB[16 * 256];   // W chunk: 16 k-rows x 256 cols
  int t = threadIdx.x;
  int rowbase = blockIdx.x * 32;
  const float* Yblk = Y + (size_t)rowbase * 256;
#pragma unroll
  for (int j = 0; j < 32; ++j) ldsA[t * 36 + j] = Yblk[j * 256 + t];  // col t, row j
  __syncthreads();
  int r0 = (t >> 6) * 8;       // 4 row-groups x 8 rows
  int c0 = (t & 63) * 4;       // 64 col-groups x 4 cols
  for (int half = 0; half < 2; ++half) {
    const float* W = half ? Wc : Wz;
    float acc[8][4];
#pragma unroll
    for (int r = 0; r < 8; ++r)
#pragma unroll
      for (int c = 0; c < 4; ++c) acc[r][c] = 0.f;
    for (int kc = 0; kc < 128; kc += 16) {
      __syncthreads();
#pragma unroll
      for (int j = 0; j < 16; ++j) ldsB[j * 256 + t] = W[(kc + j) * 256 + t];
      __syncthreads();
#pragma unroll
      for (int kk = 0; kk < 16; ++kk) {
        int ka = half * 128 + kc + kk;
        float a[8], b4[4];
        *(float4*)&a[0] = *(const float4*)&ldsA[ka * 36 + r0];
        *(float4*)&a[4] = *(const float4*)&ldsA[ka * 36 + r0 + 4];
        *(float4*)&b4[0] = *(const float4*)&ldsB[kk * 256 + c0];
#pragma unroll
        for (int r = 0; r < 8; ++r)
#pragma unroll
          for (int c = 0; c < 4; ++c) acc[r][c] += a[r] * b4[c];
      }
    }
    const float* bias = half ? bc : bz;
    float4 bi = *(const float4*)&bias[c0];
    float bb[4] = { bi.x, bi.y, bi.z, bi.w };
#pragma unroll
    for (int r = 0; r < 8; ++r) {
      ushort4 hv;
      hv.x = f2bf(tanhf(acc[r][0] + bb[0]));
      hv.y = f2bf(tanhf(acc[r][1] + bb[1]));
      hv.z = f2bf(tanhf(acc[r][2] + bb[2]));
      hv.w = f2bf(tanhf(acc[r][3] + bb[3]));
      *(ushort4*)&Hout[(size_t)(rowbase + r0 + r) * 512 + half * 256 + c0] = hv;
    }
  }
}

// ---------------- GEMM2: G3[n] = bf16( dis[n] * (H[n] @ Wo) ), H bf16 [N,512] ------
__global__ __launch_bounds__(THREADS) void k_gemm2(const unsigned short* __restrict__ H,
                                                   const float* __restrict__ Wo,
                                                   const float* __restrict__ dis,
                                                   unsigned short* __restrict__ G3) {
  __shared__ unsigned short ldsA[512 * 36];  // [k=Hcol][row] bf16, pad 36 keeps 8B align
  __shared__ float ldsB[32 * 128];           // Wo chunk: 32 k-rows x 128 cols
  int t = threadIdx.x;
  int rowbase = blockIdx.x * 32;
  const ushort2* Hblk = (const ushort2*)(H + (size_t)rowbase * 512);
#pragma unroll
  for (int j = 0; j < 32; ++j) {
    ushort2 v = Hblk[j * 256 + t];  // row j, cols 2t,2t+1
    ldsA[(2 * t) * 36 + j] = v.x;
    ldsA[(2 * t + 1) * 36 + j] = v.y;
  }
  __syncthreads();
  int r0 = (t >> 5) * 4;   // 8 row-groups x 4 rows
  int c0 = (t & 31) * 4;   // 32 col-groups x 4 cols
  float acc[4][4];
#pragma unroll
  for (int r = 0; r < 4; ++r)
#pragma unroll
    for (int c = 0; c < 4; ++c) acc[r][c] = 0.f;
  for (int kc = 0; kc < 512; kc += 32) {
    __syncthreads();
#pragma unroll
    for (int j = 0; j < 16; ++j) {
      int idx = j * 256 + t;  // 32 rows x 128 cols
      ldsB[idx] = Wo[(size_t)kc * 128 + idx];
    }
    __syncthreads();
#pragma unroll
    for (int kk = 0; kk < 32; ++kk) {
      int ka = kc + kk;
      ushort4 au = *(const ushort4*)&ldsA[ka * 36 + r0];
      float a[4] = { bf2f(au.x), bf2f(au.y), bf2f(au.z), bf2f(au.w) };
      float b4[4];
      *(float4*)&b4[0] = *(const float4*)&ldsB[kk * 128 + c0];
#pragma unroll
      for (int r = 0; r < 4; ++r)
#pragma unroll
        for (int c = 0; c < 4; ++c) acc[r][c] += a[r] * b4[c];
    }
  }
#pragma unroll
  for (int r = 0; r < 4; ++r) {
    float dd = dis[rowbase + r0 + r];
    ushort4 o;
    o.x = f2bf(acc[r][0] * dd);
    o.y = f2bf(acc[r][1] * dd);
    o.z = f2bf(acc[r][2] * dd);
    o.w = f2bf(acc[r][3] * dd);
    *(ushort4*)&G3[(size_t)(rowbase + r0 + r) * 128 + c0] = o;
  }
}

// ---------------- agg2: out[d] = dis[d]*(sum_e G3[s] + G3[d]) + bo, G3 bf16 ------------
__global__ void k_agg2(const ushort2* __restrict__ G2, const int* __restrict__ rowptr,
                       const int* __restrict__ deg, const int* __restrict__ csr,
                       const float* __restrict__ dis, const float* __restrict__ bo,
                       float2* __restrict__ out2, int n) {
  int tid = threadIdx.x;
  int d = blockIdx.x * 4 + (tid >> 6);
  if (d >= n) return;
  int lane = tid & 63;
  float ax = 0.f, ay = 0.f;
  int beg = rowptr[d];
  int end = beg + deg[d];
  int i = beg;
  for (; i + 8 <= end; i += 8) {
    int s[8]; ushort2 v[8];
#pragma unroll
    for (int j = 0; j < 8; ++j) s[j] = csr[i + j];
#pragma unroll
    for (int j = 0; j < 8; ++j) v[j] = G2[(size_t)s[j] * 64 + lane];
#pragma unroll
    for (int j = 0; j < 8; ++j) { ax += bf2f(v[j].x); ay += bf2f(v[j].y); }
  }
  for (; i < end; ++i) {
    ushort2 v = G2[(size_t)csr[i] * 64 + lane];
    ax += bf2f(v.x); ay += bf2f(v.y);
  }
  ushort2 vd = G2[(size_t)d * 64 + lane];
  float wd = dis[d];
  float2 bb = ((const float2*)bo)[lane];
  float2 o;
  o.x = (ax + bf2f(vd.x)) * wd + bb.x;
  o.y = (ay + bf2f(vd.y)) * wd + bb.y;
  out2[(size_t)d * 64 + lane] = o;
}

extern "C" void kernel_launch(void* const* d_in, const int* in_sizes, int n_in,
                              void* d_out, int out_size, void* d_ws, size_t ws_size,
                              hipStream_t stream) {
  const float* latent    = (const float*)d_in[0];
  const float* condition = (const float*)d_in[1];
  const int*   edges     = (const int*)d_in[2];
  const float* Wz        = (const float*)d_in[3];
  const float* bz        = (const float*)d_in[4];
  const float* Wc        = (const float*)d_in[5];
  const float* bc        = (const float*)d_in[6];
  const float* Wo        = (const float*)d_in[7];
  const float* bo        = (const float*)d_in[8];
  float* out = (float*)d_out;

  int n = in_sizes[0] / 128;      // 100000
  int E = in_sizes[2] / 2;        // 3200000
  const int* src = edges;
  const int* dst = edges + E;

  auto align_up = [](size_t x) { return (x + 255) & ~(size_t)255; };
  char* p = (char*)d_ws;
  int* csr     = (int*)p;   p += align_up((size_t)E * 4);
  int* rowptr  = (int*)p;   p += align_up((size_t)n * 4);
  int* deg     = (int*)p;   p += align_up((size_t)n * 4);
  int* cursor  = (int*)p;   p += align_up((size_t)n * 4);
  float* dis   = (float*)p; p += align_up((size_t)n * 4);
  int* part    = (int*)p;   p += 4096;
  // XB (n*256 bf16 = 51.2MB); G3 (n*128 bf16 = 25.6MB) aliases XB (dead after agg1)
  unsigned short* XB = (unsigned short*)p; p += align_up((size_t)n * 256 * 2);
  unsigned short* G3 = XB;
  float* YH    = (float*)p; p += align_up((size_t)n * 256 * 4);
  (void)ws_size; (void)n_in; (void)out_size;

  hipMemsetAsync(deg, 0, (size_t)n * 4, stream);
  hipMemsetAsync(cursor, 0, (size_t)n * 4, stream);

  int gE = (E + THREADS - 1) / THREADS;
  int gN = (n + THREADS - 1) / THREADS;
  int g4 = (n + 3) / 4;
  int nb = (n + 1023) / 1024;

  k_count<<<gE, THREADS, 0, stream>>>(dst, E, deg);
  k_dis<<<gN, THREADS, 0, stream>>>(deg, dis, n);
  k_scan_partial<<<nb, THREADS, 0, stream>>>(deg, n, part);
  k_scan_mid<<<1, 64, 0, stream>>>(part, nb);
  k_scan_final<<<nb, THREADS, 0, stream>>>(deg, n, part, rowptr);
  k_fill<<<gE, THREADS, 0, stream>>>(src, dst, E, rowptr, cursor, csr);

  k_cast<<<g4, THREADS, 0, stream>>>((const float4*)latent, (const float4*)condition,
                                     dis, (ushort4*)XB, n);
  k_agg1<<<g4, THREADS, 0, stream>>>((const ushort4*)XB, rowptr, deg, csr, dis,
                                     (float4*)YH, n);
  k_gemm1<<<n / 32, THREADS, 0, stream>>>(YH, (unsigned short*)YH, Wz, bz, Wc, bc);
  k_gemm2<<<n / 32, THREADS, 0, stream>>>((const unsigned short*)YH, Wo, dis, G3);
  k_agg2<<<g4, THREADS, 0, stream>>>((const ushort2*)G3, rowptr, deg, csr, dis, bo,
                                     (float2*)out, n);
}

// Round 3
// 962.779 us; speedup vs baseline: 1.6206x; 1.2840x over previous
//
#include <hip/hip_runtime.h>

#define THREADS 256

typedef __attribute__((ext_vector_type(8))) short short8;
typedef __attribute__((ext_vector_type(4))) float f32x4;
#define MFMA16(a, b, c) __builtin_amdgcn_mfma_f32_16x16x32_bf16(a, b, c, 0, 0, 0)

__device__ __forceinline__ unsigned short f2bf(float f) {
  unsigned int u = __float_as_uint(f);
  u += 0x7fffu + ((u >> 16) & 1u);
  return (unsigned short)(u >> 16);
}
__device__ __forceinline__ float bf2f(unsigned short h) {
  return __uint_as_float(((unsigned int)h) << 16);
}

// ---------------- degree count ----------------
__global__ void k_count(const int* __restrict__ dst, int E, int* __restrict__ deg) {
  int e = blockIdx.x * THREADS + threadIdx.x;
  if (e < E) atomicAdd(&deg[dst[e]], 1);
}

__global__ void k_dis(const int* __restrict__ deg, float* __restrict__ dis, int n) {
  int i = blockIdx.x * THREADS + threadIdx.x;
  if (i < n) dis[i] = rsqrtf((float)(deg[i] + 1));  // +1 self loop
}

// ---------------- exclusive scan (1024 elems / block) ----------------
__global__ void k_scan_partial(const int* __restrict__ deg, int n, int* __restrict__ part) {
  __shared__ int sd[THREADS];
  int t = threadIdx.x;
  int base = blockIdx.x * 1024 + t * 4;
  int s = 0;
#pragma unroll
  for (int j = 0; j < 4; ++j) { int idx = base + j; if (idx < n) s += deg[idx]; }
  sd[t] = s;
  __syncthreads();
  for (int off = 128; off > 0; off >>= 1) {
    if (t < off) sd[t] += sd[t + off];
    __syncthreads();
  }
  if (t == 0) part[blockIdx.x] = sd[0];
}

__global__ void k_scan_mid(int* part, int nb) {
  if (threadIdx.x == 0 && blockIdx.x == 0) {
    int run = 0;
    for (int i = 0; i < nb; ++i) { int v = part[i]; part[i] = run; run += v; }
  }
}

__global__ void k_scan_final(const int* __restrict__ deg, int n, const int* __restrict__ part,
                             int* __restrict__ rowptr) {
  __shared__ int sa[THREADS], sb[THREADS];
  int t = threadIdx.x;
  int base = blockIdx.x * 1024 + t * 4;
  int v[4]; int s = 0;
#pragma unroll
  for (int j = 0; j < 4; ++j) { int idx = base + j; v[j] = (idx < n) ? deg[idx] : 0; s += v[j]; }
  sa[t] = s;
  __syncthreads();
  int* cur = sa; int* nxt = sb;
  for (int off = 1; off < 256; off <<= 1) {
    int val = cur[t];
    if (t >= off) val += cur[t - off];
    nxt[t] = val;
    __syncthreads();
    int* tmp = cur; cur = nxt; nxt = tmp;
  }
  int pref = part[blockIdx.x] + cur[t] - s;  // exclusive prefix for this thread
#pragma unroll
  for (int j = 0; j < 4; ++j) {
    int idx = base + j;
    if (idx < n) rowptr[idx] = pref;
    pref += v[j];
  }
}

// ---------------- CSR fill ----------------
__global__ void k_fill(const int* __restrict__ src, const int* __restrict__ dst, int E,
                       const int* __restrict__ rowptr, int* __restrict__ cursor,
                       int* __restrict__ csr) {
  int e = blockIdx.x * THREADS + threadIdx.x;
  if (e < E) {
    int d = dst[e];
    int pos = atomicAdd(&cursor[d], 1);
    csr[rowptr[d] + pos] = src[e];
  }
}

// ---------------- weight transpose + bf16 cast ----------------
// WzT/WcT: [256][128] bf16 from [128][256] f32; WoT: [128][512] bf16 from [512][128] f32
__global__ void k_tw(const float* __restrict__ Wz, const float* __restrict__ Wc,
                     const float* __restrict__ Wo, unsigned short* __restrict__ WzT,
                     unsigned short* __restrict__ WcT, unsigned short* __restrict__ WoT) {
  int t = blockIdx.x * THREADS + threadIdx.x;
  if (t < 32768) {
    int c = t >> 7, k = t & 127;
    WzT[t] = f2bf(Wz[k * 256 + c]);
    WcT[t] = f2bf(Wc[k * 256 + c]);
  } else if (t < 32768 + 65536) {
    int u = t - 32768;
    int c = u >> 9, k = u & 511;
    WoT[u] = f2bf(Wo[k * 128 + c]);
  }
}

// ---------------- cast: XB[s] = bf16( dis[s] * [latent|condition][s] ), row=256 bf16 ----
__global__ void k_cast(const float4* __restrict__ lat4, const float4* __restrict__ con4,
                       const float* __restrict__ dis, ushort4* __restrict__ XB, int n) {
  int tid = threadIdx.x;
  int d = blockIdx.x * 4 + (tid >> 6);
  if (d >= n) return;
  int li = tid & 63;
  float w = dis[d];
  float4 v = (li < 32) ? lat4[(size_t)d * 32 + li] : con4[(size_t)d * 32 + (li - 32)];
  ushort4 o;
  o.x = f2bf(v.x * w); o.y = f2bf(v.y * w); o.z = f2bf(v.z * w); o.w = f2bf(v.w * w);
  XB[(size_t)d * 64 + li] = o;
}

// ---------------- agg1: Y[d] = bf16( dis[d]*(sum_e XB[s] + XB[d]) ) ----------------
__global__ void k_agg1(const ushort4* __restrict__ XB, const int* __restrict__ rowptr,
                       const int* __restrict__ deg, const int* __restrict__ csr,
                       const float* __restrict__ dis, ushort4* __restrict__ Y4, int n) {
  int tid = threadIdx.x;
  int d = blockIdx.x * 4 + (tid >> 6);
  if (d >= n) return;
  int li = tid & 63;
  float a0 = 0.f, a1 = 0.f, a2 = 0.f, a3 = 0.f;
  int beg = rowptr[d];
  int end = beg + deg[d];
  int i = beg;
  for (; i + 8 <= end; i += 8) {
    int s[8]; ushort4 v[8];
#pragma unroll
    for (int j = 0; j < 8; ++j) s[j] = csr[i + j];
#pragma unroll
    for (int j = 0; j < 8; ++j) v[j] = XB[(size_t)s[j] * 64 + li];
#pragma unroll
    for (int j = 0; j < 8; ++j) {
      a0 += bf2f(v[j].x); a1 += bf2f(v[j].y); a2 += bf2f(v[j].z); a3 += bf2f(v[j].w);
    }
  }
  for (; i < end; ++i) {
    ushort4 v = XB[(size_t)csr[i] * 64 + li];
    a0 += bf2f(v.x); a1 += bf2f(v.y); a2 += bf2f(v.z); a3 += bf2f(v.w);
  }
  ushort4 vd = XB[(size_t)d * 64 + li];
  float wd = dis[d];
  ushort4 o;
  o.x = f2bf((a0 + bf2f(vd.x)) * wd);
  o.y = f2bf((a1 + bf2f(vd.y)) * wd);
  o.z = f2bf((a2 + bf2f(vd.z)) * wd);
  o.w = f2bf((a3 + bf2f(vd.w)) * wd);
  Y4[(size_t)d * 64 + li] = o;
}

// ---------------- GEMM1 (MFMA): H = tanh([Yz@Wz + bz | Yc@Wc + bc]) bf16 -------------
// Y bf16 [N,256]; WzT/WcT bf16 [256][128]; H bf16 [N,512]. 4 waves/block, 32 rows/wave.
__global__ __launch_bounds__(THREADS) void k_gemm1m(const unsigned short* __restrict__ Y,
                                                    unsigned short* __restrict__ H,
                                                    const unsigned short* __restrict__ WzT,
                                                    const unsigned short* __restrict__ WcT,
                                                    const float* __restrict__ bz,
                                                    const float* __restrict__ bc, int n) {
  int t = threadIdx.x;
  int wave = t >> 6, lane = t & 63;
  int quad = lane >> 4, l16 = lane & 15;
  int r0 = blockIdx.x * 128 + wave * 32;
  for (int half = 0; half < 2; ++half) {
    const unsigned short* WT = half ? WcT : WzT;
    const float* bias = half ? bc : bz;
    short8 a[2][4];
#pragma unroll
    for (int rg = 0; rg < 2; ++rg) {
      int row = r0 + rg * 16 + l16;
      if (row > n - 1) row = n - 1;
      const unsigned short* yp = Y + (size_t)row * 256 + half * 128 + quad * 8;
#pragma unroll
      for (int ks = 0; ks < 4; ++ks) a[rg][ks] = *(const short8*)(yp + ks * 32);
    }
    for (int ct = 0; ct < 16; ++ct) {
      f32x4 acc0 = {0.f, 0.f, 0.f, 0.f}, acc1 = {0.f, 0.f, 0.f, 0.f};
      const unsigned short* bp = WT + (size_t)(ct * 16 + l16) * 128 + quad * 8;
#pragma unroll
      for (int ks = 0; ks < 4; ++ks) {
        short8 b = *(const short8*)(bp + ks * 32);
        acc0 = MFMA16(a[0][ks], b, acc0);
        acc1 = MFMA16(a[1][ks], b, acc1);
      }
      int col = ct * 16 + l16;
      float bb = bias[col];
#pragma unroll
      for (int rg = 0; rg < 2; ++rg) {
        f32x4 ac = rg ? acc1 : acc0;
#pragma unroll
        for (int r = 0; r < 4; ++r) {
          int row = r0 + rg * 16 + quad * 4 + r;
          if (row < n) H[(size_t)row * 512 + half * 256 + col] = f2bf(tanhf(ac[r] + bb));
        }
      }
    }
  }
}

// ---------------- GEMM2 (MFMA): G3 = bf16( dis * (H @ Wo) ) --------------------------
// H bf16 [N,512]; WoT bf16 [128][512]; G3 bf16 [N,128]. 4 waves/block, 32 rows/wave.
__global__ __launch_bounds__(THREADS) void k_gemm2m(const unsigned short* __restrict__ H,
                                                    const unsigned short* __restrict__ WoT,
                                                    const float* __restrict__ dis,
                                                    unsigned short* __restrict__ G3, int n) {
  int t = threadIdx.x;
  int wave = t >> 6, lane = t & 63;
  int quad = lane >> 4, l16 = lane & 15;
  int r0 = blockIdx.x * 128 + wave * 32;
  f32x4 acc[2][8];
#pragma unroll
  for (int rg = 0; rg < 2; ++rg)
#pragma unroll
    for (int ct = 0; ct < 8; ++ct) acc[rg][ct] = (f32x4){0.f, 0.f, 0.f, 0.f};
  int rowA0 = r0 + l16;        if (rowA0 > n - 1) rowA0 = n - 1;
  int rowA1 = r0 + 16 + l16;   if (rowA1 > n - 1) rowA1 = n - 1;
  const unsigned short* hp0 = H + (size_t)rowA0 * 512 + quad * 8;
  const unsigned short* hp1 = H + (size_t)rowA1 * 512 + quad * 8;
  for (int kc = 0; kc < 16; ++kc) {
    short8 a0 = *(const short8*)(hp0 + kc * 32);
    short8 a1 = *(const short8*)(hp1 + kc * 32);
    const unsigned short* bp = WoT + kc * 32 + quad * 8;
#pragma unroll
    for (int ct = 0; ct < 8; ++ct) {
      short8 b = *(const short8*)(bp + (size_t)(ct * 16 + l16) * 512);
      acc[0][ct] = MFMA16(a0, b, acc[0][ct]);
      acc[1][ct] = MFMA16(a1, b, acc[1][ct]);
    }
  }
#pragma unroll
  for (int rg = 0; rg < 2; ++rg)
#pragma unroll
    for (int r = 0; r < 4; ++r) {
      int row = r0 + rg * 16 + quad * 4 + r;
      if (row < n) {
        float dd = dis[row];
#pragma unroll
        for (int ct = 0; ct < 8; ++ct)
          G3[(size_t)row * 128 + ct * 16 + l16] = f2bf(acc[rg][ct][r] * dd);
      }
    }
}

// ---------------- agg2: out[d] = dis[d]*(sum_e G3[s] + G3[d]) + bo, G3 bf16 ------------
__global__ void k_agg2(const ushort2* __restrict__ G2, const int* __restrict__ rowptr,
                       const int* __restrict__ deg, const int* __restrict__ csr,
                       const float* __restrict__ dis, const float* __restrict__ bo,
                       float2* __restrict__ out2, int n) {
  int tid = threadIdx.x;
  int d = blockIdx.x * 4 + (tid >> 6);
  if (d >= n) return;
  int lane = tid & 63;
  float ax = 0.f, ay = 0.f;
  int beg = rowptr[d];
  int end = beg + deg[d];
  int i = beg;
  for (; i + 8 <= end; i += 8) {
    int s[8]; ushort2 v[8];
#pragma unroll
    for (int j = 0; j < 8; ++j) s[j] = csr[i + j];
#pragma unroll
    for (int j = 0; j < 8; ++j) v[j] = G2[(size_t)s[j] * 64 + lane];
#pragma unroll
    for (int j = 0; j < 8; ++j) { ax += bf2f(v[j].x); ay += bf2f(v[j].y); }
  }
  for (; i < end; ++i) {
    ushort2 v = G2[(size_t)csr[i] * 64 + lane];
    ax += bf2f(v.x); ay += bf2f(v.y);
  }
  ushort2 vd = G2[(size_t)d * 64 + lane];
  float wd = dis[d];
  float2 bb = ((const float2*)bo)[lane];
  float2 o;
  o.x = (ax + bf2f(vd.x)) * wd + bb.x;
  o.y = (ay + bf2f(vd.y)) * wd + bb.y;
  out2[(size_t)d * 64 + lane] = o;
}

extern "C" void kernel_launch(void* const* d_in, const int* in_sizes, int n_in,
                              void* d_out, int out_size, void* d_ws, size_t ws_size,
                              hipStream_t stream) {
  const float* latent    = (const float*)d_in[0];
  const float* condition = (const float*)d_in[1];
  const int*   edges     = (const int*)d_in[2];
  const float* Wz        = (const float*)d_in[3];
  const float* bz        = (const float*)d_in[4];
  const float* Wc        = (const float*)d_in[5];
  const float* bc        = (const float*)d_in[6];
  const float* Wo        = (const float*)d_in[7];
  const float* bo        = (const float*)d_in[8];
  float* out = (float*)d_out;

  int n = in_sizes[0] / 128;      // 100000
  int E = in_sizes[2] / 2;        // 3200000
  const int* src = edges;
  const int* dst = edges + E;

  auto align_up = [](size_t x) { return (x + 255) & ~(size_t)255; };
  char* p = (char*)d_ws;
  int* csr     = (int*)p;   p += align_up((size_t)E * 4);
  int* rowptr  = (int*)p;   p += align_up((size_t)n * 4);
  int* deg     = (int*)p;   p += align_up((size_t)n * 4);
  float* dis   = (float*)p; p += align_up((size_t)n * 4);
  int* part    = (int*)p;   p += 4096;
  unsigned short* WzT = (unsigned short*)p; p += 32768 * 2;
  unsigned short* WcT = (unsigned short*)p; p += 32768 * 2;
  unsigned short* WoT = (unsigned short*)p; p += 65536 * 2;
  unsigned short* Y  = (unsigned short*)p; p += align_up((size_t)n * 256 * 2);
  unsigned short* XB = (unsigned short*)p; p += align_up((size_t)n * 256 * 2);
  /* extra for H second half */                p += align_up((size_t)n * 256 * 2);
  unsigned short* H  = XB;                  // [N,512] bf16, aliases XB + extra
  unsigned short* G3 = Y;                   // [N,128] bf16, aliases Y (dead after gemm1)
  int* cursor = (int*)Y;                    // aliases Y (dead before agg1 writes Y)
  (void)ws_size; (void)n_in; (void)out_size;

  hipMemsetAsync(deg, 0, (size_t)n * 4, stream);
  hipMemsetAsync(cursor, 0, (size_t)n * 4, stream);

  int gE = (E + THREADS - 1) / THREADS;
  int gN = (n + THREADS - 1) / THREADS;
  int g4 = (n + 3) / 4;
  int nb = (n + 1023) / 1024;
  int gb = (n + 127) / 128;

  k_count<<<gE, THREADS, 0, stream>>>(dst, E, deg);
  k_dis<<<gN, THREADS, 0, stream>>>(deg, dis, n);
  k_scan_partial<<<nb, THREADS, 0, stream>>>(deg, n, part);
  k_scan_mid<<<1, 64, 0, stream>>>(part, nb);
  k_scan_final<<<nb, THREADS, 0, stream>>>(deg, n, part, rowptr);
  k_fill<<<gE, THREADS, 0, stream>>>(src, dst, E, rowptr, cursor, csr);
  k_tw<<<384, THREADS, 0, stream>>>(Wz, Wc, Wo, WzT, WcT, WoT);

  k_cast<<<g4, THREADS, 0, stream>>>((const float4*)latent, (const float4*)condition,
                                     dis, (ushort4*)XB, n);
  k_agg1<<<g4, THREADS, 0, stream>>>((const ushort4*)XB, rowptr, deg, csr, dis,
                                     (ushort4*)Y, n);
  k_gemm1m<<<gb, THREADS, 0, stream>>>(Y, H, WzT, WcT, bz, bc, n);
  k_gemm2m<<<gb, THREADS, 0, stream>>>(H, WoT, dis, G3, n);
  k_agg2<<<g4, THREADS, 0, stream>>>((const ushort2*)G3, rowptr, deg, csr, dis, bo,
                                     (float2*)out, n);
}

// Round 5
// 808.944 us; speedup vs baseline: 1.9288x; 1.1902x over previous
//
#include <hip/hip_runtime.h>

#define THREADS 256

typedef __attribute__((ext_vector_type(8))) short short8;
typedef __attribute__((ext_vector_type(4))) float f32x4;
#define MFMA16(a, b, c) __builtin_amdgcn_mfma_f32_16x16x32_bf16(a, b, c, 0, 0, 0)

__device__ __forceinline__ unsigned short f2bf(float f) {
  unsigned int u = __float_as_uint(f);
  u += 0x7fffu + ((u >> 16) & 1u);
  return (unsigned short)(u >> 16);
}
__device__ __forceinline__ float bf2f(unsigned short h) {
  return __uint_as_float(((unsigned int)h) << 16);
}

// ---------------- degree count ----------------
__global__ void k_count(const int* __restrict__ dst, int E, int* __restrict__ deg) {
  int e = blockIdx.x * THREADS + threadIdx.x;
  if (e < E) atomicAdd(&deg[dst[e]], 1);
}

__global__ void k_dis(const int* __restrict__ deg, float* __restrict__ dis, int n) {
  int i = blockIdx.x * THREADS + threadIdx.x;
  if (i < n) dis[i] = rsqrtf((float)(deg[i] + 1));  // +1 self loop
}

// ---------------- exclusive scan (1024 elems / block) ----------------
__global__ void k_scan_partial(const int* __restrict__ deg, int n, int* __restrict__ part) {
  __shared__ int sd[THREADS];
  int t = threadIdx.x;
  int base = blockIdx.x * 1024 + t * 4;
  int s = 0;
#pragma unroll
  for (int j = 0; j < 4; ++j) { int idx = base + j; if (idx < n) s += deg[idx]; }
  sd[t] = s;
  __syncthreads();
  for (int off = 128; off > 0; off >>= 1) {
    if (t < off) sd[t] += sd[t + off];
    __syncthreads();
  }
  if (t == 0) part[blockIdx.x] = sd[0];
}

__global__ void k_scan_mid(int* part, int nb) {
  if (threadIdx.x == 0 && blockIdx.x == 0) {
    int run = 0;
    for (int i = 0; i < nb; ++i) { int v = part[i]; part[i] = run; run += v; }
  }
}

__global__ void k_scan_final(const int* __restrict__ deg, int n, const int* __restrict__ part,
                             int* __restrict__ rowptr) {
  __shared__ int sa[THREADS], sb[THREADS];
  int t = threadIdx.x;
  int base = blockIdx.x * 1024 + t * 4;
  int v[4]; int s = 0;
#pragma unroll
  for (int j = 0; j < 4; ++j) { int idx = base + j; v[j] = (idx < n) ? deg[idx] : 0; s += v[j]; }
  sa[t] = s;
  __syncthreads();
  int* cur = sa; int* nxt = sb;
  for (int off = 1; off < 256; off <<= 1) {
    int val = cur[t];
    if (t >= off) val += cur[t - off];
    nxt[t] = val;
    __syncthreads();
    int* tmp = cur; cur = nxt; nxt = tmp;
  }
  int pref = part[blockIdx.x] + cur[t] - s;  // exclusive prefix for this thread
#pragma unroll
  for (int j = 0; j < 4; ++j) {
    int idx = base + j;
    if (idx < n) rowptr[idx] = pref;
    pref += v[j];
  }
}

// ---------------- CSR fill ----------------
__global__ void k_fill(const int* __restrict__ src, const int* __restrict__ dst, int E,
                       const int* __restrict__ rowptr, int* __restrict__ cursor,
                       int* __restrict__ csr) {
  int e = blockIdx.x * THREADS + threadIdx.x;
  if (e < E) {
    int d = dst[e];
    int pos = atomicAdd(&cursor[d], 1);
    csr[rowptr[d] + pos] = src[e];
  }
}

// ---------------- weight pack: MFMA B-fragment layout, bf16 ----------------
// WzP/WcP: [ct=16][ks=4][lane=64][8]  value = W[k = ks*32+quad*8+j][n = ct*16+l16]
// WoP:     [ct=8][kc=16][lane=64][8]  value = Wo[k = kc*32+quad*8+j][n = ct*16+l16]
__global__ void k_tw(const float* __restrict__ Wz, const float* __restrict__ Wc,
                     const float* __restrict__ Wo, unsigned short* __restrict__ WzP,
                     unsigned short* __restrict__ WcP, unsigned short* __restrict__ WoP) {
  int t = blockIdx.x * THREADS + threadIdx.x;
  if (t < 32768) {
    int ct = t >> 11, rem = t & 2047;
    int ks = rem >> 9, rem2 = rem & 511;
    int lane = rem2 >> 3, j = rem2 & 7;
    int l16 = lane & 15, quad = lane >> 4;
    int k = ks * 32 + quad * 8 + j;
    int nn = ct * 16 + l16;
    WzP[t] = f2bf(Wz[k * 256 + nn]);
    WcP[t] = f2bf(Wc[k * 256 + nn]);
  } else if (t < 32768 + 65536) {
    int u = t - 32768;
    int ct = u >> 13, rem = u & 8191;
    int kc = rem >> 9, rem2 = rem & 511;
    int lane = rem2 >> 3, j = rem2 & 7;
    int l16 = lane & 15, quad = lane >> 4;
    int k = kc * 32 + quad * 8 + j;
    int nn = ct * 16 + l16;
    WoP[u] = f2bf(Wo[k * 128 + nn]);
  }
}

// ---------------- cast: XB[s] = int8( dis[s]*x / S[s] ) + 128, S = rowmax/127 --------
__global__ void k_cast(const float4* __restrict__ lat4, const float4* __restrict__ con4,
                       const float* __restrict__ dis, unsigned int* __restrict__ XB8,
                       float* __restrict__ S, int n) {
  int tid = threadIdx.x;
  int d = blockIdx.x * 4 + (tid >> 6);
  if (d >= n) return;
  int li = tid & 63;
  float w = dis[d];
  float4 v = (li < 32) ? lat4[(size_t)d * 32 + li] : con4[(size_t)d * 32 + (li - 32)];
  v.x *= w; v.y *= w; v.z *= w; v.w *= w;
  float m = fmaxf(fmaxf(fabsf(v.x), fabsf(v.y)), fmaxf(fabsf(v.z), fabsf(v.w)));
#pragma unroll
  for (int off = 1; off < 64; off <<= 1) m = fmaxf(m, __shfl_xor(m, off, 64));
  m = fmaxf(m, 1e-20f);
  float inv = 127.0f / m;
  unsigned int u0 = (unsigned int)(int)rintf(v.x * inv) + 128u;
  unsigned int u1 = (unsigned int)(int)rintf(v.y * inv) + 128u;
  unsigned int u2 = (unsigned int)(int)rintf(v.z * inv) + 128u;
  unsigned int u3 = (unsigned int)(int)rintf(v.w * inv) + 128u;
  XB8[(size_t)d * 64 + li] = u0 | (u1 << 8) | (u2 << 16) | (u3 << 24);
  if (li == 0) S[d] = m * (1.0f / 127.0f);
}

// ---------------- agg1: Y[d] = bf16( dis[d]*(sum_e x[s] + x[d]) ), x int8+scale -------
__global__ void k_agg1(const unsigned int* __restrict__ XB8, const float* __restrict__ S,
                       const int* __restrict__ rowptr, const int* __restrict__ deg,
                       const int* __restrict__ csr, const float* __restrict__ dis,
                       ushort4* __restrict__ Y4, int n) {
  int tid = threadIdx.x;
  int d = blockIdx.x * 4 + (tid >> 6);
  if (d >= n) return;
  int li = tid & 63;
  float a0 = 0.f, a1 = 0.f, a2 = 0.f, a3 = 0.f, ssum = 0.f;
  int beg = rowptr[d];
  int end = beg + deg[d];
  int i = beg;
  for (; i + 8 <= end; i += 8) {
    int s[8]; unsigned int v[8]; float sc[8];
#pragma unroll
    for (int j = 0; j < 8; ++j) s[j] = csr[i + j];
#pragma unroll
    for (int j = 0; j < 8; ++j) { v[j] = XB8[(size_t)s[j] * 64 + li]; sc[j] = S[s[j]]; }
#pragma unroll
    for (int j = 0; j < 8; ++j) {
      a0 = fmaf((float)(v[j] & 255u), sc[j], a0);
      a1 = fmaf((float)((v[j] >> 8) & 255u), sc[j], a1);
      a2 = fmaf((float)((v[j] >> 16) & 255u), sc[j], a2);
      a3 = fmaf((float)(v[j] >> 24), sc[j], a3);
      ssum += sc[j];
    }
  }
  for (; i < end; ++i) {
    int s = csr[i];
    unsigned int v = XB8[(size_t)s * 64 + li];
    float sc = S[s];
    a0 = fmaf((float)(v & 255u), sc, a0);
    a1 = fmaf((float)((v >> 8) & 255u), sc, a1);
    a2 = fmaf((float)((v >> 16) & 255u), sc, a2);
    a3 = fmaf((float)(v >> 24), sc, a3);
    ssum += sc;
  }
  // self term
  {
    unsigned int v = XB8[(size_t)d * 64 + li];
    float sc = S[d];
    a0 = fmaf((float)(v & 255u), sc, a0);
    a1 = fmaf((float)((v >> 8) & 255u), sc, a1);
    a2 = fmaf((float)((v >> 16) & 255u), sc, a2);
    a3 = fmaf((float)(v >> 24), sc, a3);
    ssum += sc;
  }
  float bias = 128.0f * ssum;
  float wd = dis[d];
  ushort4 o;
  o.x = f2bf((a0 - bias) * wd);
  o.y = f2bf((a1 - bias) * wd);
  o.z = f2bf((a2 - bias) * wd);
  o.w = f2bf((a3 - bias) * wd);
  Y4[(size_t)d * 64 + li] = o;
}

// ---------------- GEMM1 (MFMA): H = tanh([Yz@Wz + bz | Yc@Wc + bc]) bf16 -------------
// Y bf16 [N,256]; WzP/WcP packed B-frag; H bf16 [N,512]. 4 waves/block, 32 rows/wave.
__global__ __launch_bounds__(THREADS) void k_gemm1m(const unsigned short* __restrict__ Y,
                                                    unsigned short* __restrict__ H,
                                                    const unsigned short* __restrict__ WzP,
                                                    const unsigned short* __restrict__ WcP,
                                                    const float* __restrict__ bz,
                                                    const float* __restrict__ bc, int n) {
  int t = threadIdx.x;
  int wave = t >> 6, lane = t & 63;
  int quad = lane >> 4, l16 = lane & 15;
  int r0 = blockIdx.x * 128 + wave * 32;
  for (int half = 0; half < 2; ++half) {
    const unsigned short* WP = half ? WcP : WzP;
    const float* bias = half ? bc : bz;
    short8 a[2][4];
#pragma unroll
    for (int rg = 0; rg < 2; ++rg) {
      int row = r0 + rg * 16 + l16;
      if (row > n - 1) row = n - 1;
      const unsigned short* yp = Y + (size_t)row * 256 + half * 128 + quad * 8;
#pragma unroll
      for (int ks = 0; ks < 4; ++ks) a[rg][ks] = *(const short8*)(yp + ks * 32);
    }
    for (int ct = 0; ct < 16; ++ct) {
      f32x4 acc0 = {0.f, 0.f, 0.f, 0.f}, acc1 = {0.f, 0.f, 0.f, 0.f};
      const unsigned short* bp = WP + (size_t)(ct * 4) * 512 + lane * 8;
#pragma unroll
      for (int ks = 0; ks < 4; ++ks) {
        short8 b = *(const short8*)(bp + ks * 512);
        acc0 = MFMA16(a[0][ks], b, acc0);
        acc1 = MFMA16(a[1][ks], b, acc1);
      }
      int col = ct * 16 + l16;
      float bb = bias[col];
#pragma unroll
      for (int rg = 0; rg < 2; ++rg) {
        f32x4 ac = rg ? acc1 : acc0;
#pragma unroll
        for (int r = 0; r < 4; ++r) {
          int row = r0 + rg * 16 + quad * 4 + r;
          if (row < n) H[(size_t)row * 512 + half * 256 + col] = f2bf(tanhf(ac[r] + bb));
        }
      }
    }
  }
}

// ---------------- GEMM2 (MFMA): G3 = bf16( dis * (H @ Wo) ) --------------------------
// H bf16 [N,512]; WoP packed B-frag; G3 bf16 [N,128]. 4 waves/block, 32 rows/wave.
__global__ __launch_bounds__(THREADS) void k_gemm2m(const unsigned short* __restrict__ H,
                                                    const unsigned short* __restrict__ WoP,
                                                    const float* __restrict__ dis,
                                                    unsigned short* __restrict__ G3, int n) {
  int t = threadIdx.x;
  int wave = t >> 6, lane = t & 63;
  int quad = lane >> 4, l16 = lane & 15;
  int r0 = blockIdx.x * 128 + wave * 32;
  f32x4 acc[2][8];
#pragma unroll
  for (int rg = 0; rg < 2; ++rg)
#pragma unroll
    for (int ct = 0; ct < 8; ++ct) acc[rg][ct] = (f32x4){0.f, 0.f, 0.f, 0.f};
  int rowA0 = r0 + l16;        if (rowA0 > n - 1) rowA0 = n - 1;
  int rowA1 = r0 + 16 + l16;   if (rowA1 > n - 1) rowA1 = n - 1;
  const unsigned short* hp0 = H + (size_t)rowA0 * 512 + quad * 8;
  const unsigned short* hp1 = H + (size_t)rowA1 * 512 + quad * 8;
  for (int kc = 0; kc < 16; ++kc) {
    short8 a0 = *(const short8*)(hp0 + kc * 32);
    short8 a1 = *(const short8*)(hp1 + kc * 32);
#pragma unroll
    for (int ct = 0; ct < 8; ++ct) {
      short8 b = *(const short8*)(WoP + (size_t)(ct * 16 + kc) * 512 + lane * 8);
      acc[0][ct] = MFMA16(a0, b, acc[0][ct]);
      acc[1][ct] = MFMA16(a1, b, acc[1][ct]);
    }
  }
#pragma unroll
  for (int rg = 0; rg < 2; ++rg)
#pragma unroll
    for (int r = 0; r < 4; ++r) {
      int row = r0 + rg * 16 + quad * 4 + r;
      if (row < n) {
        float dd = dis[row];
#pragma unroll
        for (int ct = 0; ct < 8; ++ct)
          G3[(size_t)row * 128 + ct * 16 + l16] = f2bf(acc[rg][ct][r] * dd);
      }
    }
}

// ---------------- agg2: out[d] = dis[d]*(sum_e G3[s] + G3[d]) + bo, G3 bf16 ------------
__global__ void k_agg2(const ushort2* __restrict__ G2, const int* __restrict__ rowptr,
                       const int* __restrict__ deg, const int* __restrict__ csr,
                       const float* __restrict__ dis, const float* __restrict__ bo,
                       float2* __restrict__ out2, int n) {
  int tid = threadIdx.x;
  int d = blockIdx.x * 4 + (tid >> 6);
  if (d >= n) return;
  int lane = tid & 63;
  float ax = 0.f, ay = 0.f;
  int beg = rowptr[d];
  int end = beg + deg[d];
  int i = beg;
  for (; i + 8 <= end; i += 8) {
    int s[8]; ushort2 v[8];
#pragma unroll
    for (int j = 0; j < 8; ++j) s[j] = csr[i + j];
#pragma unroll
    for (int j = 0; j < 8; ++j) v[j] = G2[(size_t)s[j] * 64 + lane];
#pragma unroll
    for (int j = 0; j < 8; ++j) { ax += bf2f(v[j].x); ay += bf2f(v[j].y); }
  }
  for (; i < end; ++i) {
    ushort2 v = G2[(size_t)csr[i] * 64 + lane];
    ax += bf2f(v.x); ay += bf2f(v.y);
  }
  ushort2 vd = G2[(size_t)d * 64 + lane];
  float wd = dis[d];
  float2 bb = ((const float2*)bo)[lane];
  float2 o;
  o.x = (ax + bf2f(vd.x)) * wd + bb.x;
  o.y = (ay + bf2f(vd.y)) * wd + bb.y;
  out2[(size_t)d * 64 + lane] = o;
}

extern "C" void kernel_launch(void* const* d_in, const int* in_sizes, int n_in,
                              void* d_out, int out_size, void* d_ws, size_t ws_size,
                              hipStream_t stream) {
  const float* latent    = (const float*)d_in[0];
  const float* condition = (const float*)d_in[1];
  const int*   edges     = (const int*)d_in[2];
  const float* Wz        = (const float*)d_in[3];
  const float* bz        = (const float*)d_in[4];
  const float* Wc        = (const float*)d_in[5];
  const float* bc        = (const float*)d_in[6];
  const float* Wo        = (const float*)d_in[7];
  const float* bo        = (const float*)d_in[8];
  float* out = (float*)d_out;

  int n = in_sizes[0] / 128;      // 100000
  int E = in_sizes[2] / 2;        // 3200000
  const int* src = edges;
  const int* dst = edges + E;

  auto align_up = [](size_t x) { return (x + 255) & ~(size_t)255; };
  char* p = (char*)d_ws;
  int* csr     = (int*)p;   p += align_up((size_t)E * 4);
  int* rowptr  = (int*)p;   p += align_up((size_t)n * 4);
  int* deg     = (int*)p;   p += align_up((size_t)n * 4);
  float* dis   = (float*)p; p += align_up((size_t)n * 4);
  float* S     = (float*)p; p += align_up((size_t)n * 4);
  int* part    = (int*)p;   p += 4096;
  unsigned short* WzP = (unsigned short*)p; p += 32768 * 2;
  unsigned short* WcP = (unsigned short*)p; p += 32768 * 2;
  unsigned short* WoP = (unsigned short*)p; p += 65536 * 2;
  unsigned short* Y  = (unsigned short*)p; p += align_up((size_t)n * 256 * 2);
  char* R = p; p += 2 * align_up((size_t)n * 256 * 2);   // 102.4MB region
  unsigned int* XB   = (unsigned int*)R;    // [N,64] u32 (int8 rows, 25.6MB)
  unsigned short* H  = (unsigned short*)R;  // [N,512] bf16 (102.4MB), aliases XB (dead)
  unsigned short* G3 = Y;                   // [N,128] bf16, aliases Y (dead after gemm1)
  int* cursor = (int*)Y;                    // aliases Y (dead before agg1 writes Y)
  (void)ws_size; (void)n_in; (void)out_size;

  hipMemsetAsync(deg, 0, (size_t)n * 4, stream);
  hipMemsetAsync(cursor, 0, (size_t)n * 4, stream);

  int gE = (E + THREADS - 1) / THREADS;
  int gN = (n + THREADS - 1) / THREADS;
  int g4 = (n + 3) / 4;
  int nb = (n + 1023) / 1024;
  int gb = (n + 127) / 128;

  k_count<<<gE, THREADS, 0, stream>>>(dst, E, deg);
  k_dis<<<gN, THREADS, 0, stream>>>(deg, dis, n);
  k_scan_partial<<<nb, THREADS, 0, stream>>>(deg, n, part);
  k_scan_mid<<<1, 64, 0, stream>>>(part, nb);
  k_scan_final<<<nb, THREADS, 0, stream>>>(deg, n, part, rowptr);
  k_fill<<<gE, THREADS, 0, stream>>>(src, dst, E, rowptr, cursor, csr);
  k_tw<<<512, THREADS, 0, stream>>>(Wz, Wc, Wo, WzP, WcP, WoP);

  k_cast<<<g4, THREADS, 0, stream>>>((const float4*)latent, (const float4*)condition,
                                     dis, XB, S, n);
  k_agg1<<<g4, THREADS, 0, stream>>>(XB, S, rowptr, deg, csr, dis, (ushort4*)Y, n);
  k_gemm1m<<<gb, THREADS, 0, stream>>>(Y, H, WzP, WcP, bz, bc, n);
  k_gemm2m<<<gb, THREADS, 0, stream>>>(H, WoP, dis, G3, n);
  k_agg2<<<g4, THREADS, 0, stream>>>((const ushort2*)G3, rowptr, deg, csr, dis, bo,
                                     (float2*)out, n);
}